// Round 12
// baseline (541.468 us; speedup 1.0000x reference)
//
#include <hip/hip_runtime.h>

#define H_   128
#define W_   128
#define HW_  (H_*W_)

typedef __attribute__((ext_vector_type(8))) short  short8;
typedef __attribute__((ext_vector_type(8))) __bf16 bf16x8;
typedef __attribute__((ext_vector_type(4))) float  f32x4;

__device__ __forceinline__ ushort bf16r(float f) {
    uint u = __builtin_bit_cast(uint, f);
    u += 0x7fff + ((u >> 16) & 1);          // RNE
    return (ushort)(u >> 16);
}
__device__ __forceinline__ float ubf_lo(uint p) {
    return __builtin_bit_cast(float, p << 16);
}
__device__ __forceinline__ float ubf_hi(uint p) {
    return __builtin_bit_cast(float, p & 0xffff0000u);
}

// ---------------------------------------------------------------------------
// prep: K-reordered bf16 weights.
// Chunk t<8: k = cc*8 + c_l  (taps 0..7, channels t*8+c_l)
// Chunk t=8: k = c           (tap 8, all 64 channels)
// wB [9][64 co][64 k], owB [9][16 j][64 k] (j>=4 rows zero)
// ---------------------------------------------------------------------------
__global__ void prep_kernel(const float* __restrict__ wt, const float* __restrict__ ow,
                            ushort* __restrict__ wB, ushort* __restrict__ owB)
{
    int idx = blockIdx.x * 256 + threadIdx.x;
    if (idx < 9 * 64 * 64) {
        int t  = idx >> 12;
        int co = (idx >> 6) & 63;
        int k  = idx & 63;
        int cc, c;
        if (t < 8) { cc = k >> 3; c = t * 8 + (k & 7); }
        else       { cc = 8;      c = k; }
        wB[idx] = bf16r(wt[(co * 64 + c) * 9 + cc]);
    }
    if (idx < 9 * 16 * 64) {
        int t = idx >> 10;
        int j = (idx >> 6) & 15;
        int k = idx & 63;
        float v = 0.f;
        if (j < 4) {
            int cc, c;
            if (t < 8) { cc = k >> 3; c = t * 8 + (k & 7); }
            else       { cc = 8;      c = k; }
            v = ow[(j * 64 + c) * 9 + cc];
        }
        owB[idx] = bf16r(v);
    }
}

// ---------------------------------------------------------------------------
// main: fused offsets-conv (pass 1, MFMA) + gather + einsum (pass 2, MFMA).
// Block: 256 threads = 4 waves; pixels = rows (h0,h0+1) x 128 w; each wave
// owns 64px x 64co. Grid 512, XCD-swizzled: b = blk&7, hp = blk>>3.
// ---------------------------------------------------------------------------
__global__ __launch_bounds__(256, 3) void main_kernel(
    const float* __restrict__ x, const ushort* __restrict__ wB,
    const ushort* __restrict__ owB, const float* __restrict__ ob,
    float* __restrict__ out)
{
    __shared__ __align__(16) ushort a_lds[256][72];   // 36.9 KB
    __shared__ __align__(16) ushort w_lds[64][72];    //  9.2 KB

    int tid  = threadIdx.x;
    int blk  = blockIdx.x;
    int b    = blk & 7;
    int h0   = (blk >> 3) << 1;
    int row  = tid >> 7, w = tid & 127;
    int h    = h0 + row;
    int lane = tid & 63, wid = tid >> 6;

    const float* xb = x + ((size_t)b << 20);          // b * 64 * 16384

    // =================== PASS 1: offsets conv via MFMA ===================
    f32x4 acc_o[4];
    #pragma unroll
    for (int i = 0; i < 4; ++i) acc_o[i] = (f32x4){0.f, 0.f, 0.f, 0.f};

    for (int t = 0; t < 9; ++t) {
        if (tid < 128) {            // stage owB chunk: 16x64 shorts
            *(uint4*)&w_lds[tid >> 3][(tid & 7) * 8] =
                ((const uint4*)(owB + t * 1024))[tid];
        }
        if (t < 8) {
            #pragma unroll
            for (int cc = 0; cc < 8; ++cc) {
                int ki = cc / 3, kj = cc - (cc / 3) * 3;
                int y = h - 1 + ki, xw = w - 1 + kj;
                bool vv = ((unsigned)y < (unsigned)H_) && ((unsigned)xw < (unsigned)W_);
                int ia = (y << 7) + xw;
                uint pk[4];
                #pragma unroll
                for (int e = 0; e < 4; ++e) {
                    const float* p0 = xb + ((size_t)(t * 8 + 2 * e) << 14);
                    const float* p1 = p0 + 16384;
                    float s0 = vv ? p0[ia] : 0.f;
                    float s1 = vv ? p1[ia] : 0.f;
                    pk[e] = (uint)bf16r(s0) | ((uint)bf16r(s1) << 16);
                }
                *(uint4*)&a_lds[tid][cc * 8] = make_uint4(pk[0], pk[1], pk[2], pk[3]);
            }
        } else {                    // tap 8: y=h+1, x=w+1, all 64 channels
            int y = h + 1, xw = w + 1;
            bool vv = (y < H_) && (xw < W_);
            int ia = (y << 7) + xw;
            #pragma unroll
            for (int c8 = 0; c8 < 8; ++c8) {
                uint pk[4];
                #pragma unroll
                for (int e = 0; e < 4; ++e) {
                    const float* p0 = xb + ((size_t)(c8 * 8 + 2 * e) << 14);
                    const float* p1 = p0 + 16384;
                    float s0 = vv ? p0[ia] : 0.f;
                    float s1 = vv ? p1[ia] : 0.f;
                    pk[e] = (uint)bf16r(s0) | ((uint)bf16r(s1) << 16);
                }
                *(uint4*)&a_lds[tid][c8 * 8] = make_uint4(pk[0], pk[1], pk[2], pk[3]);
            }
        }
        __syncthreads();
        #pragma unroll
        for (int s = 0; s < 2; ++s) {
            int krow = s * 32 + (lane >> 4) * 8;
            bf16x8 bfr = __builtin_bit_cast(bf16x8,
                *(const short8*)&w_lds[lane & 15][krow]);
            #pragma unroll
            for (int i = 0; i < 4; ++i) {
                bf16x8 af = __builtin_bit_cast(bf16x8,
                    *(const short8*)&a_lds[wid * 64 + i * 16 + (lane & 15)][krow]);
                acc_o[i] = __builtin_amdgcn_mfma_f32_16x16x32_bf16(af, bfr, acc_o[i], 0, 0, 0);
            }
        }
        __syncthreads();
    }

    // redistribute o through LDS (reuse w_lds as float[4][256])
    float* o_f = (float*)&w_lds[0][0];
    {
        int j4 = lane & 15;
        if (j4 < 4) {
            float bias = ob[j4];
            #pragma unroll
            for (int i = 0; i < 4; ++i) {
                int pxb = wid * 64 + i * 16 + ((lane >> 4) << 2);
                #pragma unroll
                for (int r = 0; r < 4; ++r)
                    o_f[j4 * 256 + pxb + r] = acc_o[i][r] + bias;
            }
        }
    }
    __syncthreads();
    float t_ = o_f[tid];
    float bo = o_f[256 + tid];
    float l_ = o_f[512 + tid];
    float r_ = o_f[768 + tid];

    // ---- geometry for the 9 taps (registers; byte offsets + bf16 1-D wts) ----
    uint g_ad[9][4];
    uint g_wy[9], g_wx[9];
    #pragma unroll
    for (int cc = 0; cc < 9; ++cc) {
        float dy, dx;
        switch (cc) {
            case 0: dy = t_;  dx = 0.f; break;
            case 1: dy = bo;  dx = t_;  break;
            case 2: dy = 0.f; dx = bo;  break;
            case 3: dy = t_;  dx = 0.f; break;
            case 4: dy = bo;  dx = l_;  break;
            case 5: dy = l_;  dx = l_;  break;
            case 6: dy = 0.f; dx = 0.f; break;
            case 7: dy = 0.f; dx = r_;  break;
            default: dy = r_; dx = r_;  break;
        }
        float py  = (float)(h - 1 + cc / 3) + dy;
        float pxf = (float)(w - 1 + cc - (cc / 3) * 3) + dx;
        float y0f = floorf(py), x0f = floorf(pxf);
        float ly = py - y0f, lx = pxf - x0f;
        int y0 = (int)y0f, x0 = (int)x0f;
        int y1 = y0 + 1,   x1 = x0 + 1;
        int y0c = min(max(y0, 0), H_ - 1), y1c = min(max(y1, 0), H_ - 1);
        int x0c = min(max(x0, 0), W_ - 1), x1c = min(max(x1, 0), W_ - 1);
        g_ad[cc][0] = (uint)((((y0c << 7) + x0c) << 2));
        g_ad[cc][1] = (uint)((((y0c << 7) + x1c) << 2));
        g_ad[cc][2] = (uint)((((y1c << 7) + x0c) << 2));
        g_ad[cc][3] = (uint)((((y1c << 7) + x1c) << 2));
        float ay0 = ((unsigned)y0 < (unsigned)H_) ? 1.f - ly : 0.f;
        float ay1 = ((unsigned)y1 < (unsigned)H_) ? ly : 0.f;
        float ax0 = ((unsigned)x0 < (unsigned)W_) ? 1.f - lx : 0.f;
        float ax1 = ((unsigned)x1 < (unsigned)W_) ? lx : 0.f;
        g_wy[cc] = (uint)bf16r(ay0) | ((uint)bf16r(ay1) << 16);
        g_wx[cc] = (uint)bf16r(ax0) | ((uint)bf16r(ax1) << 16);
    }
    __syncthreads();   // everyone done reading o_f before pass-2 staging

    // =================== PASS 2: gather + einsum ===================
    f32x4 acc[4][4];
    #pragma unroll
    for (int i = 0; i < 4; ++i)
        #pragma unroll
        for (int j = 0; j < 4; ++j) acc[i][j] = (f32x4){0.f, 0.f, 0.f, 0.f};

    for (int t = 0; t < 9; ++t) {
        {   // stage wB chunk: 64x64 shorts = 512 uint4
            const uint4* src = (const uint4*)(wB + t * 4096);
            #pragma unroll
            for (int q = 0; q < 2; ++q) {
                int i = tid + q * 256;
                *(uint4*)&w_lds[i >> 3][(i & 7) * 8] = src[i];
            }
        }
        if (t < 8) {
            #pragma unroll
            for (int cc = 0; cc < 8; ++cc) {
                uint a0 = g_ad[cc][0], a1 = g_ad[cc][1];
                uint a2 = g_ad[cc][2], a3 = g_ad[cc][3];
                float ay0 = ubf_lo(g_wy[cc]), ay1 = ubf_hi(g_wy[cc]);
                float ax0 = ubf_lo(g_wx[cc]), ax1 = ubf_hi(g_wx[cc]);
                float w00 = ay0 * ax0, w01 = ay0 * ax1;
                float w10 = ay1 * ax0, w11 = ay1 * ax1;
                uint pk[4];
                #pragma unroll
                for (int e = 0; e < 4; ++e) {
                    const char* p0 = (const char*)(xb + ((size_t)(t * 8 + 2 * e) << 14));
                    const char* p1 = p0 + 65536;
                    float s0 = w00 * *(const float*)(p0 + a0)
                             + w01 * *(const float*)(p0 + a1)
                             + w10 * *(const float*)(p0 + a2)
                             + w11 * *(const float*)(p0 + a3);
                    float s1 = w00 * *(const float*)(p1 + a0)
                             + w01 * *(const float*)(p1 + a1)
                             + w10 * *(const float*)(p1 + a2)
                             + w11 * *(const float*)(p1 + a3);
                    pk[e] = (uint)bf16r(s0) | ((uint)bf16r(s1) << 16);
                }
                *(uint4*)&a_lds[tid][cc * 8] = make_uint4(pk[0], pk[1], pk[2], pk[3]);
            }
        } else {   // tap 8 for all 64 channels
            uint a0 = g_ad[8][0], a1 = g_ad[8][1];
            uint a2 = g_ad[8][2], a3 = g_ad[8][3];
            float ay0 = ubf_lo(g_wy[8]), ay1 = ubf_hi(g_wy[8]);
            float ax0 = ubf_lo(g_wx[8]), ax1 = ubf_hi(g_wx[8]);
            float w00 = ay0 * ax0, w01 = ay0 * ax1;
            float w10 = ay1 * ax0, w11 = ay1 * ax1;
            #pragma unroll
            for (int c8 = 0; c8 < 8; ++c8) {
                uint pk[4];
                #pragma unroll
                for (int e = 0; e < 4; ++e) {
                    const char* p0 = (const char*)(xb + ((size_t)(c8 * 8 + 2 * e) << 14));
                    const char* p1 = p0 + 65536;
                    float s0 = w00 * *(const float*)(p0 + a0)
                             + w01 * *(const float*)(p0 + a1)
                             + w10 * *(const float*)(p0 + a2)
                             + w11 * *(const float*)(p0 + a3);
                    float s1 = w00 * *(const float*)(p1 + a0)
                             + w01 * *(const float*)(p1 + a1)
                             + w10 * *(const float*)(p1 + a2)
                             + w11 * *(const float*)(p1 + a3);
                    pk[e] = (uint)bf16r(s0) | ((uint)bf16r(s1) << 16);
                }
                *(uint4*)&a_lds[tid][c8 * 8] = make_uint4(pk[0], pk[1], pk[2], pk[3]);
            }
        }
        __syncthreads();
        #pragma unroll
        for (int s = 0; s < 2; ++s) {
            int krow = s * 32 + (lane >> 4) * 8;
            bf16x8 af[4];
            #pragma unroll
            for (int i = 0; i < 4; ++i)
                af[i] = __builtin_bit_cast(bf16x8,
                    *(const short8*)&a_lds[wid * 64 + i * 16 + (lane & 15)][krow]);
            #pragma unroll
            for (int j = 0; j < 4; ++j) {
                bf16x8 bfr = __builtin_bit_cast(bf16x8,
                    *(const short8*)&w_lds[j * 16 + (lane & 15)][krow]);
                #pragma unroll
                for (int i = 0; i < 4; ++i)
                    acc[i][j] = __builtin_amdgcn_mfma_f32_16x16x32_bf16(
                        af[i], bfr, acc[i][j], 0, 0, 0);
            }
        }
        __syncthreads();
    }

    // ---- epilogue ----
    #pragma unroll
    for (int i = 0; i < 4; ++i) {
        int px = wid * 64 + i * 16 + ((lane >> 4) << 2);
        int hh = h0 + (px >> 7);
        int ww = px & 127;
        #pragma unroll
        for (int j = 0; j < 4; ++j) {
            int co = j * 16 + (lane & 15);
            *(float4*)&out[(((size_t)(b * 64 + co)) * H_ + hh) * W_ + ww] =
                *(float4*)&acc[i][j];
        }
    }
}

extern "C" void kernel_launch(void* const* d_in, const int* in_sizes, int n_in,
                              void* d_out, int out_size, void* d_ws, size_t ws_size,
                              hipStream_t stream)
{
    const float* x  = (const float*)d_in[0];
    const float* ow = (const float*)d_in[1];
    const float* ob = (const float*)d_in[2];
    const float* wt = (const float*)d_in[3];
    float* out = (float*)d_out;

    ushort* wB  = (ushort*)d_ws;            // 9*64*64 = 36864 shorts
    ushort* owB = wB + 9 * 64 * 64;         // 9*16*64 =  9216 shorts

    prep_kernel<<<dim3(144), dim3(256), 0, stream>>>(wt, ow, wB, owB);
    main_kernel<<<dim3(512), dim3(256), 0, stream>>>(x, wB, owB, ob, out);
}